// Round 2
// baseline (3121.465 us; speedup 1.0000x reference)
//
#include <hip/hip_runtime.h>
#include <cstdint>
#include <cstddef>

typedef unsigned long long u64;

#define B_ 512
#define T_ 1024
#define I_ 128
#define H_ 256

// -----------------------------------------------------------------------------
// All arithmetic is strict float32 mimicking a numpy/BLAS transliteration of
// the reference: every dot product is a single ascending-index chain starting
// at 0.0f (bias added AFTER), every recurrence op rounded separately.
// __f*_rn intrinsics forbid contraction; spike flips are the only failure mode.
// -----------------------------------------------------------------------------

// Kernel 1: cur1 chain + mem1 recursion + spk1 bitmasks.
// 512 blocks x 256 thr. Block = (batch-group grp, h-block hblk). Wave g ->
// batch grp*4+g; lanes = 64 h channels. W1 chunk in LDS [i][hl] (b32 reads,
// conflict-free); x staged 4 timesteps at a time (wave-uniform LDS reads).
__global__ __launch_bounds__(256) void k_spk1(
    const float* __restrict__ x, const float* __restrict__ W1,
    const float* __restrict__ b1, const float* __restrict__ beta1,
    u64* __restrict__ spk1bits)
{
  __shared__ float w1t[I_ * 64];   // [i][hl]   32 KB
  __shared__ float xs[4 * 4 * I_]; // [g][tt][i] 8 KB
  const int tid = threadIdx.x, hblk = blockIdx.x & 3, grp = blockIdx.x >> 2;
  const int lane = tid & 63, g = tid >> 6, b = grp * 4 + g, h = hblk * 64 + lane;

  for (int k = tid; k < 64 * I_; k += 256) {
    int i = k & 127, hl = k >> 7;
    w1t[i * 64 + hl] = W1[(hblk * 64 + hl) * I_ + i];
  }
  const float b1f = b1[h];
  const float bt1 = fminf(fmaxf(beta1[0], 0.f), 1.f);
  float mem = 0.f;
  __syncthreads();

  for (int tc = 0; tc < T_; tc += 4) {
    for (int k = tid; k < 2048; k += 256) {
      int i = k & 127, row = k >> 7, tt = row & 3, gg = row >> 2;
      xs[(gg * 4 + tt) * I_ + i] =
          x[(((size_t)(grp * 4 + gg)) * T_ + (tc + tt)) * I_ + i];
    }
    __syncthreads();

    // ascending-i FMA chains from 0 (BLAS sgemm micro-kernel order)
    float a0 = 0.f, a1 = 0.f, a2 = 0.f, a3 = 0.f;
    const float* xg = xs + g * 4 * I_;
    for (int i = 0; i < I_; ++i) {
      float wv = w1t[i * 64 + lane];
      a0 = __fmaf_rn(xg[i],          wv, a0);
      a1 = __fmaf_rn(xg[I_ + i],     wv, a1);
      a2 = __fmaf_rn(xg[2 * I_ + i], wv, a2);
      a3 = __fmaf_rn(xg[3 * I_ + i], wv, a3);
    }
    float accs[4] = {a0, a1, a2, a3};
    #pragma unroll
    for (int tt = 0; tt < 4; ++tt) {
      float cur = __fadd_rn(accs[tt], b1f);            // einsum result + b1
      float r = (mem > 1.f) ? 1.f : 0.f;               // reset from PREV mem
      mem = __fsub_rn(__fadd_rn(__fmul_rn(bt1, mem), cur), r);
      u64 m = __ballot(mem > 1.f);
      if (lane == 0) spk1bits[((size_t)b * T_ + (tc + tt)) * 4 + hblk] = m;
    }
    __syncthreads();  // WAR before restaging xs
  }
}

// Kernel 2: mem2 recursion + spk2 bitmasks. 256 blocks x 512 thr.
// Block = (j-half jh, batch-group grp); j = tid&127, batch g = tid>>7.
// Half of W2^T in LDS (128 KB): w2t[h][j]. cur2 chain = ascending-h walk of
// set spike bits (exactly sgemm's k-chain for binary input), + b2 after.
// Sync-free main loop; spike words are wave-uniform scalars.
__global__ __launch_bounds__(512) void k_mem2(
    const u64* __restrict__ spk1bits,
    const float* __restrict__ W2, const float* __restrict__ b2,
    const float* __restrict__ beta2,
    u64* __restrict__ spk2bits)
{
  extern __shared__ float w2t[];  // [256][128]
  const int tid = threadIdx.x, jh = blockIdx.x & 1, grp = blockIdx.x >> 1;
  const int j = tid & 127, g = tid >> 7, b = grp * 4 + g, J0 = jh * 128;
  const int whalf = (tid >> 6) & 1;  // which 64-j half of this block

  for (int k = tid; k < 128 * H_; k += 512) {
    int hh = k & 255, jj = k >> 8;
    w2t[hh * 128 + jj] = W2[(J0 + jj) * H_ + hh];
  }
  const float b2f = b2[J0 + j];
  const float bt2 = fminf(fmaxf(beta2[0], 0.f), 1.f);
  float mem2 = 0.f;
  __syncthreads();

  const u64* sb = spk1bits + (size_t)b * T_ * 4;
  u64* so = spk2bits + (size_t)b * T_ * 4;

  for (int t = 0; t < T_; ++t) {
    float acc = 0.f;
    #pragma unroll
    for (int wi = 0; wi < 4; ++wi) {
      u64 w = sb[t * 4 + wi];
      unsigned lo = __builtin_amdgcn_readfirstlane((unsigned)w);
      unsigned hi = __builtin_amdgcn_readfirstlane((unsigned)(w >> 32));
      u64 bits = ((u64)hi << 32) | lo;       // scalar -> SALU bit walk
      const float* base = w2t + wi * 64 * 128 + j;
      // 4-deep batched gathers to hide LDS latency; order stays ascending.
      while (__builtin_popcountll(bits) >= 4) {
        int p0 = __builtin_ctzll(bits); bits &= bits - 1;
        int p1 = __builtin_ctzll(bits); bits &= bits - 1;
        int p2 = __builtin_ctzll(bits); bits &= bits - 1;
        int p3 = __builtin_ctzll(bits); bits &= bits - 1;
        float v0 = base[p0 * 128], v1 = base[p1 * 128];
        float v2 = base[p2 * 128], v3 = base[p3 * 128];
        acc = __fadd_rn(acc, v0); acc = __fadd_rn(acc, v1);
        acc = __fadd_rn(acc, v2); acc = __fadd_rn(acc, v3);
      }
      while (bits) {
        int p = __builtin_ctzll(bits); bits &= bits - 1;
        acc = __fadd_rn(acc, base[p * 128]);
      }
    }
    float cur2 = __fadd_rn(acc, b2f);
    float r = (mem2 > 1.f) ? 1.f : 0.f;
    mem2 = __fsub_rn(__fadd_rn(__fmul_rn(bt2, mem2), cur2), r);
    u64 m2 = __ballot(mem2 > 1.f);
    if ((tid & 63) == 0) so[t * 4 + jh * 2 + whalf] = m2;
  }
}

// Kernel 3: out[b,t] = (ascending-j chain of Wout over spk2 bits) + bout.
// One thread per (b,t): chains independent, latency hidden by 524k threads.
__global__ __launch_bounds__(256) void k_out(
    const u64* __restrict__ spk2bits, const float* __restrict__ Wout,
    const float* __restrict__ bout, float* __restrict__ outpre)
{
  __shared__ float wl[H_];
  __shared__ float bo;
  const int tid = threadIdx.x;
  if (tid < H_) wl[tid] = Wout[tid];
  if (tid == 0) bo = bout[0];
  __syncthreads();
  const size_t idx = (size_t)blockIdx.x * 256 + tid;  // idx = b*T + t
  const u64* p = spk2bits + idx * 4;
  float c = 0.f;
  #pragma unroll
  for (int wi = 0; wi < 4; ++wi) {
    u64 bits = p[wi];
    const float* base = wl + wi * 64;
    while (bits) {
      int q = __builtin_ctzll(bits); bits &= bits - 1;
      c = __fadd_rn(c, base[q]);
    }
  }
  outpre[idx] = __fadd_rn(c, bo);
}

// Kernel 4: memo leaky-integrator scan per batch (serial in t, exact order).
__global__ __launch_bounds__(256) void k_memo(
    const float* __restrict__ outpre, const float* __restrict__ beta_out,
    float* __restrict__ out)
{
  const int b = blockIdx.x * 256 + threadIdx.x;  // 0..511
  const float bto = fminf(fmaxf(beta_out[0], 0.f), 1.f);
  float memo = 0.f;
  const float* ip = outpre + (size_t)b * T_;
  float* op = out + (size_t)b * T_;
  for (int t = 0; t < T_; ++t) {
    memo = __fadd_rn(__fmul_rn(bto, memo), ip[t]);
    op[t] = memo;
  }
}

extern "C" void kernel_launch(void* const* d_in, const int* in_sizes, int n_in,
                              void* d_out, int out_size, void* d_ws, size_t ws_size,
                              hipStream_t stream) {
  const float* x        = (const float*)d_in[0];
  const float* W1       = (const float*)d_in[1];
  const float* b1       = (const float*)d_in[2];
  const float* W2       = (const float*)d_in[3];
  const float* b2       = (const float*)d_in[4];
  const float* Wout     = (const float*)d_in[5];
  const float* bout     = (const float*)d_in[6];
  const float* beta1    = (const float*)d_in[7];
  const float* beta2    = (const float*)d_in[8];
  const float* beta_out = (const float*)d_in[9];

  // ws layout: spk1 bits 16 MB | spk2 bits 16 MB | outpre 2 MB  (~35.7 MB)
  u64*   spk1bits = (u64*)d_ws;
  u64*   spk2bits = (u64*)((char*)d_ws + 16777216);
  float* outpre   = (float*)((char*)d_ws + 33554432);
  float* out      = (float*)d_out;

  (void)hipFuncSetAttribute((const void*)k_mem2,
      hipFuncAttributeMaxDynamicSharedMemorySize, 131072);

  k_spk1<<<dim3(512), dim3(256), 0, stream>>>(x, W1, b1, beta1, spk1bits);
  k_mem2<<<dim3(256), dim3(512), 131072, stream>>>(spk1bits, W2, b2, beta2,
                                                   spk2bits);
  k_out<<<dim3(2048), dim3(256), 0, stream>>>(spk2bits, Wout, bout, outpre);
  k_memo<<<dim3(2), dim3(256), 0, stream>>>(outpre, beta_out, out);
}